// Round 9
// baseline (814.633 us; speedup 1.0000x reference)
//
#include <hip/hip_runtime.h>

#define T_SEQ 4096
#define C_EMB 2048
#define NH 16
#define NKV 4
#define HD 128

typedef short bf16x8 __attribute__((ext_vector_type(8)));
typedef float f32x4 __attribute__((ext_vector_type(4)));
typedef unsigned short u16x4 __attribute__((ext_vector_type(4)));

__device__ inline unsigned short f2bf(float f) {
    unsigned int u = __float_as_uint(f);
    unsigned int r = (u + 0x7FFFu + ((u >> 16) & 1u)) >> 16;
    return (unsigned short)r;
}

// async global->LDS 16B per lane; lds base must be wave-uniform (lane*16 auto-added)
__device__ __forceinline__ void async_cp16(const unsigned short* g, unsigned short* l) {
    __builtin_amdgcn_global_load_lds((const __attribute__((address_space(1))) unsigned int*)g,
                                     (__attribute__((address_space(3))) unsigned int*)l,
                                     16, 0, 0);
}

// ---------------- fp32 -> bf16 elementwise ----------------
__global__ __launch_bounds__(256) void cvt_bf16(const float* __restrict__ in,
                                                unsigned short* __restrict__ out, int n) {
    int i = (blockIdx.x * 256 + threadIdx.x) * 4;
    if (i >= n) return;
    float4 f = *(const float4*)(&in[i]);
    u16x4 o;
    o.x = f2bf(f.x); o.y = f2bf(f.y); o.z = f2bf(f.z); o.w = f2bf(f.w);
    *(u16x4*)(&out[i]) = o;
}

// ---------------- merged weight transposes: 4 matrices in one launch ----------------
__global__ __launch_bounds__(256) void transpose_all(const float* __restrict__ wq,
                                                     const float* __restrict__ wk,
                                                     const float* __restrict__ wv,
                                                     const float* __restrict__ wo,
                                                     unsigned short* __restrict__ wqkvT,
                                                     unsigned short* __restrict__ woT) {
    __shared__ float tile[32][33];
    int z = blockIdx.z;
    const float* in;
    unsigned short* out;
    int ld_in;
    if (z == 0)      { in = wq; out = wqkvT;                         ld_in = 2048; }
    else if (z == 1) { in = wk; out = wqkvT + (size_t)2048 * 2048;   ld_in = 512;  }
    else if (z == 2) { in = wv; out = wqkvT + (size_t)2560 * 2048;   ld_in = 512;  }
    else             { in = wo; out = woT;                           ld_in = 2048; }
    if ((z == 1 || z == 2) && blockIdx.x >= 16) return;

    int x = blockIdx.x * 32 + threadIdx.x;
    for (int i = threadIdx.y; i < 32; i += 8) {
        int y = blockIdx.y * 32 + i;
        tile[i][threadIdx.x] = in[(size_t)y * ld_in + x];
    }
    __syncthreads();
    int xo = blockIdx.y * 32 + threadIdx.x;
    for (int i = threadIdx.y; i < 32; i += 8) {
        int yo = blockIdx.x * 32 + i;
        out[(size_t)yo * 2048 + xo] = f2bf(tile[threadIdx.x][i]);
    }
}

// ==== Fused QKV projection + RoPE + RMSNorm + V-transpose (frozen from R5) ====
__global__ __launch_bounds__(256, 3) void gemm_qkv(const unsigned short* __restrict__ A,
                                                   const unsigned short* __restrict__ Bt,
                                                   const float* __restrict__ cosb,
                                                   const float* __restrict__ sinb,
                                                   unsigned short* __restrict__ Qn,
                                                   unsigned short* __restrict__ Kn,
                                                   unsigned short* __restrict__ Vt) {
    __shared__ __align__(16) unsigned short As[3][128 * 32];
    __shared__ __align__(16) unsigned short Bs[3][128 * 32];
    const int K = 2048;
    int t = threadIdx.x;
    int w = t >> 6, lane = t & 63;
    int ln = lane & 15, q = lane >> 4;
    int wm = w * 32;

    // XCD-rectangle swizzle: grid 24x32 = 768 = 8 XCDs x (12 cols x 8 rows)
    int d = blockIdx.y * 24 + blockIdx.x;
    int xcd = d & 7, l = d >> 3;
    int lx = l % 12, ly = l / 12;
    int bx = (xcd & 1) * 12 + lx;
    int by = (xcd >> 1) * 8 + ly;
    int m0 = by * 128, n0 = bx * 128;

    f32x4 acc[2][8] = {};

    int r0 = t >> 2, c0 = (t & 3) ^ ((t >> 4) & 3);
    int L1 = 256 + t;
    int r1 = L1 >> 2, c1 = (L1 & 3) ^ ((L1 >> 4) & 3);
    const unsigned short* a0 = &A[(size_t)(m0 + r0) * K + c0 * 8];
    const unsigned short* a1 = &A[(size_t)(m0 + r1) * K + c1 * 8];
    const unsigned short* b0 = &Bt[(size_t)(n0 + r0) * K + c0 * 8];
    const unsigned short* b1 = &Bt[(size_t)(n0 + r1) * K + c1 * 8];

    auto stage = [&](int b, int k0) {
        async_cp16(a0 + k0, &As[b][w * 512]);
        async_cp16(a1 + k0, &As[b][2048 + w * 512]);
        async_cp16(b0 + k0, &Bs[b][w * 512]);
        async_cp16(b1 + k0, &Bs[b][2048 + w * 512]);
    };

    stage(0, 0);
    stage(1, 32);

    int bc = 0;
    for (int it = 0; it < 64; ++it) {
        if (it < 63) asm volatile("s_waitcnt vmcnt(4)" ::: "memory");
        else         asm volatile("s_waitcnt vmcnt(0)" ::: "memory");
        __builtin_amdgcn_s_barrier();
        __builtin_amdgcn_sched_barrier(0);
        if (it < 62) {
            int bn = bc + 2; if (bn >= 3) bn -= 3;
            stage(bn, (it + 2) * 32);
        }
        int cs = (q ^ ((ln >> 2) & 3)) * 8;
        bf16x8 af[2], bfr[8];
#pragma unroll
        for (int i = 0; i < 2; ++i) af[i] = *(const bf16x8*)(&As[bc][(wm + i * 16 + ln) * 32 + cs]);
#pragma unroll
        for (int j = 0; j < 8; ++j) bfr[j] = *(const bf16x8*)(&Bs[bc][(j * 16 + ln) * 32 + cs]);
#pragma unroll
        for (int i = 0; i < 2; ++i)
#pragma unroll
            for (int j = 0; j < 8; ++j)
                acc[i][j] = __builtin_amdgcn_mfma_f32_16x16x32_bf16(af[i], bfr[j], acc[i][j], 0, 0, 0);
        bc = (bc == 2) ? 0 : bc + 1;
    }

    // ---- fused epilogue ----
    if (n0 < 2560) {
        bool isQ = (n0 < 2048);
        int h = isQ ? (n0 >> 7) : ((n0 - 2048) >> 7);
#pragma unroll
        for (int i = 0; i < 2; ++i)
#pragma unroll
            for (int r = 0; r < 4; ++r) {
                int row = m0 + wm + i * 16 + q * 4 + r;
                float y1[4], y2[4];
                float ss = 0.0f;
#pragma unroll
                for (int j = 0; j < 4; ++j) {
                    float a = acc[i][j][r];
                    float b = acc[i][j + 4][r];
                    float cc = cosb[row * 64 + j * 16 + ln];
                    float sv = sinb[row * 64 + j * 16 + ln];
                    y1[j] = a * cc + b * sv;
                    y2[j] = b * cc - a * sv;
                    ss += y1[j] * y1[j] + y2[j] * y2[j];
                }
                ss += __shfl_xor(ss, 1);
                ss += __shfl_xor(ss, 2);
                ss += __shfl_xor(ss, 4);
                ss += __shfl_xor(ss, 8);
                float rv = rsqrtf(ss * (1.0f / 128.0f) + 1e-6f);
                if (isQ) {
                    float s = rv * (0.08838834764831845f * 1.4426950408889634f);
                    unsigned short* ob = Qn + (size_t)row * 2048 + h * 128;
#pragma unroll
                    for (int j = 0; j < 4; ++j) {
                        ob[j * 16 + ln] = f2bf(y1[j] * s);
                        ob[64 + j * 16 + ln] = f2bf(y2[j] * s);
                    }
                } else {
                    unsigned short* ob = Kn + (size_t)row * 512 + h * 128;
#pragma unroll
                    for (int j = 0; j < 4; ++j) {
                        ob[j * 16 + ln] = f2bf(y1[j] * rv);
                        ob[64 + j * 16 + ln] = f2bf(y2[j] * rv);
                    }
                }
            }
    } else {
        int v0 = n0 - 2560;
        unsigned short* sm = &As[0][0];
#pragma unroll
        for (int half = 0; half < 2; ++half) {
            __syncthreads();
#pragma unroll
            for (int i = 0; i < 2; ++i)
#pragma unroll
                for (int jj = 0; jj < 4; ++jj) {
                    int j = half * 4 + jj;
                    int cc = jj * 16 + ln;
                    int rr = wm + i * 16 + q * 4;
                    u16x4 pk;
                    pk.x = f2bf(acc[i][j][0]); pk.y = f2bf(acc[i][j][1]);
                    pk.z = f2bf(acc[i][j][2]); pk.w = f2bf(acc[i][j][3]);
                    *(u16x4*)(&sm[cc * 136 + rr]) = pk;
                }
            __syncthreads();
            int vtr = t >> 2, mseg = (t & 3) * 32;
            unsigned short* dst = Vt + (size_t)(v0 + half * 64 + vtr) * 4096 + m0 + mseg;
            const unsigned short* src = &sm[vtr * 136 + mseg];
            *(int4*)(dst)      = *(const int4*)(src);
            *(int4*)(dst + 8)  = *(const int4*)(src + 8);
            *(int4*)(dst + 16) = *(const int4*)(src + 16);
            *(int4*)(dst + 24) = *(const int4*)(src + 24);
        }
    }
}

// ---------------- bf16 GEMM (out-proj) v12 (frozen from R8) ----------------
__global__ __launch_bounds__(512, 2) void gemm_bt_v12(const unsigned short* __restrict__ A,
                                                      const unsigned short* __restrict__ Bt,
                                                      float* __restrict__ C, int M, int N, int K) {
    __shared__ __align__(16) unsigned short As[2][256 * 64];
    __shared__ __align__(16) unsigned short Bs[2][128 * 64];
    int t = threadIdx.x;
    int w = t >> 6, lane = t & 63;
    int ln = lane & 15, q = lane >> 4;
    int wr = w >> 1, wc = w & 1;
    int m0 = blockIdx.y * 256, n0 = blockIdx.x * 128;

    f32x4 acc[4][4] = {};

    const unsigned short* ab[4];
    const unsigned short* bb[2];
#pragma unroll
    for (int s = 0; s < 4; ++s) {
        int L = s * 512 + t;
        int r = L >> 3;
        int c = (L & 7) ^ (r & 7);
        ab[s] = &A[(size_t)(m0 + r) * K + c * 8];
    }
#pragma unroll
    for (int s = 0; s < 2; ++s) {
        int L = s * 512 + t;
        int r = L >> 3;
        int c = (L & 7) ^ (r & 7);
        bb[s] = &Bt[(size_t)(n0 + r) * K + c * 8];
    }

    auto stage = [&](int b, int k0) {
#pragma unroll
        for (int s = 0; s < 4; ++s) async_cp16(ab[s] + k0, &As[b][s * 4096 + w * 512]);
#pragma unroll
        for (int s = 0; s < 2; ++s) async_cp16(bb[s] + k0, &Bs[b][s * 4096 + w * 512]);
    };

    stage(0, 0);
    asm volatile("s_waitcnt vmcnt(0)" ::: "memory");
    __builtin_amdgcn_s_barrier();

    int buf = 0;
    for (int it = 0; it < 32; ++it) {
        if (it < 31) stage(buf ^ 1, (it + 1) * 64);
#pragma unroll
        for (int kk = 0; kk < 2; ++kk) {
            bf16x8 bfr[4];
#pragma unroll
            for (int j = 0; j < 4; ++j) {
                int row = wc * 64 + j * 16 + ln;
                bfr[j] = *(const bf16x8*)(&Bs[buf][row * 64 + (((kk * 4 + q) ^ (row & 7)) * 8)]);
            }
#pragma unroll
            for (int i = 0; i < 4; ++i) {
                int row = wr * 64 + i * 16 + ln;
                bf16x8 a = *(const bf16x8*)(&As[buf][row * 64 + (((kk * 4 + q) ^ (row & 7)) * 8)]);
#pragma unroll
                for (int j = 0; j < 4; ++j)
                    acc[i][j] = __builtin_amdgcn_mfma_f32_16x16x32_bf16(a, bfr[j], acc[i][j], 0, 0, 0);
            }
        }
        asm volatile("s_waitcnt vmcnt(0)" ::: "memory");
        __builtin_amdgcn_s_barrier();
        buf ^= 1;
    }

#pragma unroll
    for (int i = 0; i < 4; ++i)
#pragma unroll
        for (int j = 0; j < 4; ++j)
#pragma unroll
            for (int r = 0; r < 4; ++r) {
                int row = m0 + wr * 64 + i * 16 + q * 4 + r;
                int col = n0 + wc * 64 + j * 16 + ln;
                C[(size_t)row * N + col] = acc[i][j][r];
            }
}

// ---------------- Flash attention v6-keysplit ----------------
// 4 waves = 2 q-groups x 2 key-groups. Wave (qg,kg): 32 q-rows (qg), 32-key half-tile (kg).
// Halves per-wave K/V LDS reads (8 kf + 8 vf + 2 pa vs 34 b128). Q in regs (2 tiles).
// Fixed-max softmax => per-wave partial (o,l) are plain sums; kg-pair combines only at
// output (2x per block) exchanging hd-halves of o through the free K/V buffer (prefetch
// for the swap iteration is issued AFTER the exchange). Same grid/pairing/occupancy.
__global__ __launch_bounds__(256) void flash_attn(const unsigned short* __restrict__ Qn,
                                                  const unsigned short* __restrict__ Kn,
                                                  const unsigned short* __restrict__ Vt,
                                                  unsigned short* __restrict__ Ao) {
    __shared__ __align__(16) unsigned short Ks[2][64 * 128];
    __shared__ __align__(16) unsigned short Vs[2][128 * 64];
    __shared__ __align__(16) unsigned short Pl[4][32 * 40];
    __shared__ float lsh[2][2][32];

    int pairi = blockIdx.x;
    int h = blockIdx.y;
    int kvh = h >> 2;
    int t = threadIdx.x;
    int w = t >> 6, lane = t & 63;
    int ln = lane & 15, q = lane >> 4;
    int qg = w >> 1, kg = w & 1;

    int nA = 64 - pairi;
    int bq = 63 - pairi;
    int wq0 = bq * 64;

    bf16x8 qf[2][4];
    {
        const unsigned short* qb0 = Qn + (size_t)(wq0 + qg * 32 + ln) * 2048 + h * 128;
        const unsigned short* qb1 = Qn + (size_t)(wq0 + qg * 32 + 16 + ln) * 2048 + h * 128;
#pragma unroll
        for (int kc = 0; kc < 4; ++kc) {
            qf[0][kc] = *(const bf16x8*)(qb0 + kc * 32 + q * 8);
            qf[1][kc] = *(const bf16x8*)(qb1 + kc * 32 + q * 8);
        }
    }

    f32x4 o[2][8] = {};
    f32x4 l_p[2] = {};

    // hoisted per-thread staging bases (unchanged pattern from v4.1)
    const unsigned short* kbase[4];
    const unsigned short* vbase[4];
#pragma unroll
    for (int s = 0; s < 4; ++s) {
        int L = s * 256 + t;
        int key = L >> 4;
        int ck = (L & 15) ^ (key & 15);
        kbase[s] = Kn + (size_t)key * 512 + kvh * 128 + ck * 8;
        int hd = L >> 3;
        int cv = (L & 7) ^ (hd & 7);
        vbase[s] = Vt + (size_t)(kvh * 128 + hd) * 4096 + cv * 8;
    }

#pragma unroll
    for (int s = 0; s < 4; ++s) async_cp16(kbase[s], &Ks[0][s * 2048 + w * 512]);
#pragma unroll
    for (int s = 0; s < 4; ++s) async_cp16(vbase[s], &Vs[0][s * 2048 + w * 512]);

    // output+combine helper logic is inlined twice (swap point and end)
    for (int it = 0; it < 65; ++it) {
        __syncthreads();

        int nxt = it + 1;

        if (it == nA) {
            // ---- combine across kg pair + output, using free buffers [nxt&1] as scratch ----
            int fb = nxt & 1;
            float* osh = (qg == 0) ? (float*)&Ks[fb][0] : (float*)&Vs[fb][0];
            int nb = (kg ^ 1) * 4;   // non-kept f base
#pragma unroll
            for (int qi = 0; qi < 2; ++qi)
#pragma unroll
                for (int fi = 0; fi < 4; ++fi)
#pragma unroll
                    for (int r = 0; r < 4; ++r)
                        osh[kg * 2048 + ((qi * 4 + fi) * 4 + r) * 64 + lane] = o[qi][nb + fi][r];
            float l_red[2][4];
#pragma unroll
            for (int qi = 0; qi < 2; ++qi)
#pragma unroll
                for (int r = 0; r < 4; ++r) {
                    float s = l_p[qi][r];
                    s += __shfl_xor(s, 1); s += __shfl_xor(s, 2);
                    s += __shfl_xor(s, 4); s += __shfl_xor(s, 8);
                    l_red[qi][r] = s;
                    if (ln == 0) lsh[qg][kg][qi * 16 + q * 4 + r] = s;
                }
            __syncthreads();
#pragma unroll
            for (int qi = 0; qi < 2; ++qi)
#pragma unroll
                for (int r = 0; r < 4; ++r) {
                    float inv = 1.0f / (l_red[qi][r] + lsh[qg][kg ^ 1][qi * 16 + q * 4 + r]);
                    int row = wq0 + qg * 32 + qi * 16 + q * 4 + r;
                    unsigned short* ob = Ao + (size_t)row * 2048 + h * 128;
#pragma unroll
                    for (int fi = 0; fi < 4; ++fi) {
                        int f = kg * 4 + fi;
                        float v = o[qi][f][r] + osh[(kg ^ 1) * 2048 + ((qi * 4 + fi) * 4 + r) * 64 + lane];
                        ob[f * 16 + ln] = f2bf(v * inv);
                    }
                }
            __syncthreads();
            // reset for second q-block
            bq = pairi; wq0 = bq * 64;
            const unsigned short* qb0 = Qn + (size_t)(wq0 + qg * 32 + ln) * 2048 + h * 128;
            const unsigned short* qb1 = Qn + (size_t)(wq0 + qg * 32 + 16 + ln) * 2048 + h * 128;
#pragma unroll
            for (int kc = 0; kc < 4; ++kc) {
                qf[0][kc] = *(const bf16x8*)(qb0 + kc * 32 + q * 8);
                qf[1][kc] = *(const bf16x8*)(qb1 + kc * 32 + q * 8);
            }
#pragma unroll
            for (int qi = 0; qi < 2; ++qi) {
#pragma unroll
                for (int f = 0; f < 8; ++f) o[qi][f] = (f32x4){0.f, 0.f, 0.f, 0.f};
                l_p[qi] = (f32x4){0.f, 0.f, 0.f, 0.f};
            }
        }

        if (nxt < 65) {
            int nkt = (nxt < nA) ? nxt * 64 : (nxt - nA) * 64;
            size_t koff = (size_t)nkt * 512;
            unsigned short* kd = Ks[nxt & 1];
            unsigned short* vd = Vs[nxt & 1];
#pragma unroll
            for (int s = 0; s < 4; ++s) async_cp16(kbase[s] + koff, kd + s * 2048 + w * 512);
#pragma unroll
            for (int s = 0; s < 4; ++s) async_cp16(vbase[s] + nkt, vd + s * 2048 + w * 512);
        }

        int kt0 = (it < nA) ? it * 64 : (it - nA) * 64;
        const unsigned short* kb = Ks[it & 1];
        const unsigned short* vb = Vs[it & 1];

        // QK^T: 2 q-tiles x 2 key-subtiles (this wave's 32-key half)
        f32x4 sA[2][2];
#pragma unroll
        for (int qi = 0; qi < 2; ++qi)
#pragma unroll
            for (int kj = 0; kj < 2; ++kj)
                sA[qi][kj] = (f32x4){-16.6f, -16.6f, -16.6f, -16.6f};

        __builtin_amdgcn_s_setprio(1);
#pragma unroll
        for (int kj = 0; kj < 2; ++kj) {
            int key = kg * 32 + kj * 16 + ln;
#pragma unroll
            for (int kc = 0; kc < 4; ++kc) {
                bf16x8 kf = *(const bf16x8*)(&kb[key * 128 + (((kc * 4 + q) ^ ln) * 8)]);
                sA[0][kj] = __builtin_amdgcn_mfma_f32_16x16x32_bf16(qf[0][kc], kf, sA[0][kj], 0, 0, 0);
                sA[1][kj] = __builtin_amdgcn_mfma_f32_16x16x32_bf16(qf[1][kc], kf, sA[1][kj], 0, 0, 0);
            }
        }
        __builtin_amdgcn_s_setprio(0);

        if (kt0 + kg * 32 + 31 > wq0 + qg * 32) {
#pragma unroll
            for (int qi = 0; qi < 2; ++qi)
#pragma unroll
                for (int kj = 0; kj < 2; ++kj)
#pragma unroll
                    for (int r = 0; r < 4; ++r) {
                        int key = kt0 + kg * 32 + kj * 16 + ln;
                        int row = wq0 + qg * 32 + qi * 16 + q * 4 + r;
                        if (key > row) sA[qi][kj][r] = -3e38f;
                    }
        }

#pragma unroll
        for (int qi = 0; qi < 2; ++qi)
#pragma unroll
            for (int r = 0; r < 4; ++r) {
                int prow = (qi * 16 + q * 4 + r) * 40;
#pragma unroll
                for (int kj = 0; kj < 2; ++kj) {
                    float p = __builtin_amdgcn_exp2f(sA[qi][kj][r]);
                    Pl[w][prow + kj * 16 + ln] = (unsigned short)(__float_as_uint(p) >> 16);
                    l_p[qi][r] += p;
                }
            }

        // PV: k-depth 32 (this wave's keys); each vf feeds both q-tiles
        bf16x8 pa0 = *(const bf16x8*)(&Pl[w][ln * 40 + q * 8]);
        bf16x8 pa1 = *(const bf16x8*)(&Pl[w][(16 + ln) * 40 + q * 8]);
        __builtin_amdgcn_s_setprio(1);
#pragma unroll
        for (int f = 0; f < 8; ++f) {
            bf16x8 vf = *(const bf16x8*)(&vb[(f * 16 + ln) * 64 + (((kg * 4 + q) ^ (ln & 7)) * 8)]);
            o[0][f] = __builtin_amdgcn_mfma_f32_16x16x32_bf16(pa0, vf, o[0][f], 0, 0, 0);
            o[1][f] = __builtin_amdgcn_mfma_f32_16x16x32_bf16(pa1, vf, o[1][f], 0, 0, 0);
        }
        __builtin_amdgcn_s_setprio(0);
    }

    // ---- final combine + output (scratch = buffers[1], both idle) ----
    {
        int fb = 1;
        float* osh = (qg == 0) ? (float*)&Ks[fb][0] : (float*)&Vs[fb][0];
        int nb = (kg ^ 1) * 4;
#pragma unroll
        for (int qi = 0; qi < 2; ++qi)
#pragma unroll
            for (int fi = 0; fi < 4; ++fi)
#pragma unroll
                for (int r = 0; r < 4; ++r)
                    osh[kg * 2048 + ((qi * 4 + fi) * 4 + r) * 64 + lane] = o[qi][nb + fi][r];
        float l_red[2][4];
#pragma unroll
        for (int qi = 0; qi < 2; ++qi)
#pragma unroll
            for (int r = 0; r < 4; ++r) {
                float s = l_p[qi][r];
                s += __shfl_xor(s, 1); s += __shfl_xor(s, 2);
                s += __shfl_xor(s, 4); s += __shfl_xor(s, 8);
                l_red[qi][r] = s;
                if (ln == 0) lsh[qg][kg][qi * 16 + q * 4 + r] = s;
            }
        __syncthreads();
#pragma unroll
        for (int qi = 0; qi < 2; ++qi)
#pragma unroll
            for (int r = 0; r < 4; ++r) {
                float inv = 1.0f / (l_red[qi][r] + lsh[qg][kg ^ 1][qi * 16 + q * 4 + r]);
                int row = wq0 + qg * 32 + qi * 16 + q * 4 + r;
                unsigned short* ob = Ao + (size_t)row * 2048 + h * 128;
#pragma unroll
                for (int fi = 0; fi < 4; ++fi) {
                    int f = kg * 4 + fi;
                    float v = o[qi][f][r] + osh[(kg ^ 1) * 2048 + ((qi * 4 + fi) * 4 + r) * 64 + lane];
                    ob[f * 16 + ln] = f2bf(v * inv);
                }
            }
    }
}

extern "C" void kernel_launch(void* const* d_in, const int* in_sizes, int n_in,
                              void* d_out, int out_size, void* d_ws, size_t ws_size,
                              hipStream_t stream) {
    const float* x    = (const float*)d_in[0];
    const float* cosb = (const float*)d_in[1];
    const float* sinb = (const float*)d_in[2];
    const float* wq   = (const float*)d_in[3];
    const float* wk   = (const float*)d_in[4];
    const float* wv   = (const float*)d_in[5];
    const float* wo   = (const float*)d_in[6];
    float* out = (float*)d_out;

    char* ws = (char*)d_ws;
    unsigned short* xb    = (unsigned short*)ws;               // [4096][2048]
    unsigned short* wqkvT = xb    + (size_t)4096 * 2048;       // [3072][2048]
    unsigned short* woT   = wqkvT + (size_t)3072 * 2048;       // [2048][2048]
    unsigned short* Qn    = woT   + (size_t)2048 * 2048;       // [4096][2048]
    unsigned short* Kn    = Qn    + (size_t)4096 * 2048;       // [4096][512]
    unsigned short* Vt    = Kn    + (size_t)4096 * 512;        // [512][4096]
    unsigned short* Ao    = Vt    + (size_t)512 * 4096;        // [4096][2048]

    cvt_bf16<<<(4096 * 2048 / 4 + 255) / 256, 256, 0, stream>>>(x, xb, 4096 * 2048);
    transpose_all<<<dim3(64, 64, 4), dim3(32, 8), 0, stream>>>(wq, wk, wv, wo, wqkvT, woT);
    gemm_qkv<<<dim3(24, 32), 256, 0, stream>>>(xb, wqkvT, cosb, sinb, Qn, Kn, Vt);
    flash_attn<<<dim3(32, 16), 256, 0, stream>>>(Qn, Kn, Vt, Ao);
    gemm_bt_v12<<<dim3(16, 16), 512, 0, stream>>>(Ao, woT, out, 4096, 2048, 2048);
}

// Round 10
// 356.289 us; speedup vs baseline: 2.2864x; 2.2864x over previous
//
#include <hip/hip_runtime.h>

#define T_SEQ 4096
#define C_EMB 2048
#define NH 16
#define NKV 4
#define HD 128

typedef short bf16x8 __attribute__((ext_vector_type(8)));
typedef float f32x4 __attribute__((ext_vector_type(4)));
typedef unsigned short u16x4 __attribute__((ext_vector_type(4)));

__device__ inline unsigned short f2bf(float f) {
    unsigned int u = __float_as_uint(f);
    unsigned int r = (u + 0x7FFFu + ((u >> 16) & 1u)) >> 16;
    return (unsigned short)r;
}

// async global->LDS 16B per lane; lds base must be wave-uniform (lane*16 auto-added)
__device__ __forceinline__ void async_cp16(const unsigned short* g, unsigned short* l) {
    __builtin_amdgcn_global_load_lds((const __attribute__((address_space(1))) unsigned int*)g,
                                     (__attribute__((address_space(3))) unsigned int*)l,
                                     16, 0, 0);
}

// ---------------- fp32 -> bf16 elementwise ----------------
__global__ __launch_bounds__(256) void cvt_bf16(const float* __restrict__ in,
                                                unsigned short* __restrict__ out, int n) {
    int i = (blockIdx.x * 256 + threadIdx.x) * 4;
    if (i >= n) return;
    float4 f = *(const float4*)(&in[i]);
    u16x4 o;
    o.x = f2bf(f.x); o.y = f2bf(f.y); o.z = f2bf(f.z); o.w = f2bf(f.w);
    *(u16x4*)(&out[i]) = o;
}

// ---------------- merged weight transposes: 4 matrices in one launch ----------------
__global__ __launch_bounds__(256) void transpose_all(const float* __restrict__ wq,
                                                     const float* __restrict__ wk,
                                                     const float* __restrict__ wv,
                                                     const float* __restrict__ wo,
                                                     unsigned short* __restrict__ wqkvT,
                                                     unsigned short* __restrict__ woT) {
    __shared__ float tile[32][33];
    int z = blockIdx.z;
    const float* in;
    unsigned short* out;
    int ld_in;
    if (z == 0)      { in = wq; out = wqkvT;                         ld_in = 2048; }
    else if (z == 1) { in = wk; out = wqkvT + (size_t)2048 * 2048;   ld_in = 512;  }
    else if (z == 2) { in = wv; out = wqkvT + (size_t)2560 * 2048;   ld_in = 512;  }
    else             { in = wo; out = woT;                           ld_in = 2048; }
    if ((z == 1 || z == 2) && blockIdx.x >= 16) return;

    int x = blockIdx.x * 32 + threadIdx.x;
    for (int i = threadIdx.y; i < 32; i += 8) {
        int y = blockIdx.y * 32 + i;
        tile[i][threadIdx.x] = in[(size_t)y * ld_in + x];
    }
    __syncthreads();
    int xo = blockIdx.y * 32 + threadIdx.x;
    for (int i = threadIdx.y; i < 32; i += 8) {
        int yo = blockIdx.x * 32 + i;
        out[(size_t)yo * 2048 + xo] = f2bf(tile[threadIdx.x][i]);
    }
}

// ==== Fused QKV projection + RoPE + RMSNorm + V-transpose (frozen from R5) ====
__global__ __launch_bounds__(256, 3) void gemm_qkv(const unsigned short* __restrict__ A,
                                                   const unsigned short* __restrict__ Bt,
                                                   const float* __restrict__ cosb,
                                                   const float* __restrict__ sinb,
                                                   unsigned short* __restrict__ Qn,
                                                   unsigned short* __restrict__ Kn,
                                                   unsigned short* __restrict__ Vt) {
    __shared__ __align__(16) unsigned short As[3][128 * 32];
    __shared__ __align__(16) unsigned short Bs[3][128 * 32];
    const int K = 2048;
    int t = threadIdx.x;
    int w = t >> 6, lane = t & 63;
    int ln = lane & 15, q = lane >> 4;
    int wm = w * 32;

    // XCD-rectangle swizzle: grid 24x32 = 768 = 8 XCDs x (12 cols x 8 rows)
    int d = blockIdx.y * 24 + blockIdx.x;
    int xcd = d & 7, l = d >> 3;
    int lx = l % 12, ly = l / 12;
    int bx = (xcd & 1) * 12 + lx;
    int by = (xcd >> 1) * 8 + ly;
    int m0 = by * 128, n0 = bx * 128;

    f32x4 acc[2][8] = {};

    int r0 = t >> 2, c0 = (t & 3) ^ ((t >> 4) & 3);
    int L1 = 256 + t;
    int r1 = L1 >> 2, c1 = (L1 & 3) ^ ((L1 >> 4) & 3);
    const unsigned short* a0 = &A[(size_t)(m0 + r0) * K + c0 * 8];
    const unsigned short* a1 = &A[(size_t)(m0 + r1) * K + c1 * 8];
    const unsigned short* b0 = &Bt[(size_t)(n0 + r0) * K + c0 * 8];
    const unsigned short* b1 = &Bt[(size_t)(n0 + r1) * K + c1 * 8];

    auto stage = [&](int b, int k0) {
        async_cp16(a0 + k0, &As[b][w * 512]);
        async_cp16(a1 + k0, &As[b][2048 + w * 512]);
        async_cp16(b0 + k0, &Bs[b][w * 512]);
        async_cp16(b1 + k0, &Bs[b][2048 + w * 512]);
    };

    stage(0, 0);
    stage(1, 32);

    int bc = 0;
    for (int it = 0; it < 64; ++it) {
        if (it < 63) asm volatile("s_waitcnt vmcnt(4)" ::: "memory");
        else         asm volatile("s_waitcnt vmcnt(0)" ::: "memory");
        __builtin_amdgcn_s_barrier();
        __builtin_amdgcn_sched_barrier(0);
        if (it < 62) {
            int bn = bc + 2; if (bn >= 3) bn -= 3;
            stage(bn, (it + 2) * 32);
        }
        int cs = (q ^ ((ln >> 2) & 3)) * 8;
        bf16x8 af[2], bfr[8];
#pragma unroll
        for (int i = 0; i < 2; ++i) af[i] = *(const bf16x8*)(&As[bc][(wm + i * 16 + ln) * 32 + cs]);
#pragma unroll
        for (int j = 0; j < 8; ++j) bfr[j] = *(const bf16x8*)(&Bs[bc][(j * 16 + ln) * 32 + cs]);
#pragma unroll
        for (int i = 0; i < 2; ++i)
#pragma unroll
            for (int j = 0; j < 8; ++j)
                acc[i][j] = __builtin_amdgcn_mfma_f32_16x16x32_bf16(af[i], bfr[j], acc[i][j], 0, 0, 0);
        bc = (bc == 2) ? 0 : bc + 1;
    }

    // ---- fused epilogue ----
    if (n0 < 2560) {
        bool isQ = (n0 < 2048);
        int h = isQ ? (n0 >> 7) : ((n0 - 2048) >> 7);
#pragma unroll
        for (int i = 0; i < 2; ++i)
#pragma unroll
            for (int r = 0; r < 4; ++r) {
                int row = m0 + wm + i * 16 + q * 4 + r;
                float y1[4], y2[4];
                float ss = 0.0f;
#pragma unroll
                for (int j = 0; j < 4; ++j) {
                    float a = acc[i][j][r];
                    float b = acc[i][j + 4][r];
                    float cc = cosb[row * 64 + j * 16 + ln];
                    float sv = sinb[row * 64 + j * 16 + ln];
                    y1[j] = a * cc + b * sv;
                    y2[j] = b * cc - a * sv;
                    ss += y1[j] * y1[j] + y2[j] * y2[j];
                }
                ss += __shfl_xor(ss, 1);
                ss += __shfl_xor(ss, 2);
                ss += __shfl_xor(ss, 4);
                ss += __shfl_xor(ss, 8);
                float rv = rsqrtf(ss * (1.0f / 128.0f) + 1e-6f);
                if (isQ) {
                    float s = rv * (0.08838834764831845f * 1.4426950408889634f);
                    unsigned short* ob = Qn + (size_t)row * 2048 + h * 128;
#pragma unroll
                    for (int j = 0; j < 4; ++j) {
                        ob[j * 16 + ln] = f2bf(y1[j] * s);
                        ob[64 + j * 16 + ln] = f2bf(y2[j] * s);
                    }
                } else {
                    unsigned short* ob = Kn + (size_t)row * 512 + h * 128;
#pragma unroll
                    for (int j = 0; j < 4; ++j) {
                        ob[j * 16 + ln] = f2bf(y1[j] * rv);
                        ob[64 + j * 16 + ln] = f2bf(y2[j] * rv);
                    }
                }
            }
    } else {
        int v0 = n0 - 2560;
        unsigned short* sm = &As[0][0];
#pragma unroll
        for (int half = 0; half < 2; ++half) {
            __syncthreads();
#pragma unroll
            for (int i = 0; i < 2; ++i)
#pragma unroll
                for (int jj = 0; jj < 4; ++jj) {
                    int j = half * 4 + jj;
                    int cc = jj * 16 + ln;
                    int rr = wm + i * 16 + q * 4;
                    u16x4 pk;
                    pk.x = f2bf(acc[i][j][0]); pk.y = f2bf(acc[i][j][1]);
                    pk.z = f2bf(acc[i][j][2]); pk.w = f2bf(acc[i][j][3]);
                    *(u16x4*)(&sm[cc * 136 + rr]) = pk;
                }
            __syncthreads();
            int vtr = t >> 2, mseg = (t & 3) * 32;
            unsigned short* dst = Vt + (size_t)(v0 + half * 64 + vtr) * 4096 + m0 + mseg;
            const unsigned short* src = &sm[vtr * 136 + mseg];
            *(int4*)(dst)      = *(const int4*)(src);
            *(int4*)(dst + 8)  = *(const int4*)(src + 8);
            *(int4*)(dst + 16) = *(const int4*)(src + 16);
            *(int4*)(dst + 24) = *(const int4*)(src + 24);
        }
    }
}

// ---------------- bf16 GEMM (out-proj) v12 (frozen from R8) ----------------
__global__ __launch_bounds__(512, 2) void gemm_bt_v12(const unsigned short* __restrict__ A,
                                                      const unsigned short* __restrict__ Bt,
                                                      float* __restrict__ C, int M, int N, int K) {
    __shared__ __align__(16) unsigned short As[2][256 * 64];
    __shared__ __align__(16) unsigned short Bs[2][128 * 64];
    int t = threadIdx.x;
    int w = t >> 6, lane = t & 63;
    int ln = lane & 15, q = lane >> 4;
    int wr = w >> 1, wc = w & 1;
    int m0 = blockIdx.y * 256, n0 = blockIdx.x * 128;

    f32x4 acc[4][4] = {};

    const unsigned short* ab[4];
    const unsigned short* bb[2];
#pragma unroll
    for (int s = 0; s < 4; ++s) {
        int L = s * 512 + t;
        int r = L >> 3;
        int c = (L & 7) ^ (r & 7);
        ab[s] = &A[(size_t)(m0 + r) * K + c * 8];
    }
#pragma unroll
    for (int s = 0; s < 2; ++s) {
        int L = s * 512 + t;
        int r = L >> 3;
        int c = (L & 7) ^ (r & 7);
        bb[s] = &Bt[(size_t)(n0 + r) * K + c * 8];
    }

    auto stage = [&](int b, int k0) {
#pragma unroll
        for (int s = 0; s < 4; ++s) async_cp16(ab[s] + k0, &As[b][s * 4096 + w * 512]);
#pragma unroll
        for (int s = 0; s < 2; ++s) async_cp16(bb[s] + k0, &Bs[b][s * 4096 + w * 512]);
    };

    stage(0, 0);
    asm volatile("s_waitcnt vmcnt(0)" ::: "memory");
    __builtin_amdgcn_s_barrier();

    int buf = 0;
    for (int it = 0; it < 32; ++it) {
        if (it < 31) stage(buf ^ 1, (it + 1) * 64);
#pragma unroll
        for (int kk = 0; kk < 2; ++kk) {
            bf16x8 bfr[4];
#pragma unroll
            for (int j = 0; j < 4; ++j) {
                int row = wc * 64 + j * 16 + ln;
                bfr[j] = *(const bf16x8*)(&Bs[buf][row * 64 + (((kk * 4 + q) ^ (row & 7)) * 8)]);
            }
#pragma unroll
            for (int i = 0; i < 4; ++i) {
                int row = wr * 64 + i * 16 + ln;
                bf16x8 a = *(const bf16x8*)(&As[buf][row * 64 + (((kk * 4 + q) ^ (row & 7)) * 8)]);
#pragma unroll
                for (int j = 0; j < 4; ++j)
                    acc[i][j] = __builtin_amdgcn_mfma_f32_16x16x32_bf16(a, bfr[j], acc[i][j], 0, 0, 0);
            }
        }
        asm volatile("s_waitcnt vmcnt(0)" ::: "memory");
        __builtin_amdgcn_s_barrier();
        buf ^= 1;
    }

#pragma unroll
    for (int i = 0; i < 4; ++i)
#pragma unroll
        for (int j = 0; j < 4; ++j)
#pragma unroll
            for (int r = 0; r < 4; ++r) {
                int row = m0 + wr * 64 + i * 16 + q * 4 + r;
                int col = n0 + wc * 64 + j * 16 + ln;
                C[(size_t)row * N + col] = acc[i][j][r];
            }
}

// ---------------- Flash attention v6-keysplit-b: STATIC accumulator indexing ----------------
// Same algorithm as R9 (2 q-groups x 2 key-groups, halved per-wave K/V LDS reads), but
// the kg-pair combine uses if(kg==0)/else branches with LITERAL o[][] indices (rule #20:
// the R9 version's runtime index nb+fi demoted o[2][8] to scratch -> 2.2GB spill traffic).
__global__ __launch_bounds__(256) void flash_attn(const unsigned short* __restrict__ Qn,
                                                  const unsigned short* __restrict__ Kn,
                                                  const unsigned short* __restrict__ Vt,
                                                  unsigned short* __restrict__ Ao) {
    __shared__ __align__(16) unsigned short Ks[2][64 * 128];
    __shared__ __align__(16) unsigned short Vs[2][128 * 64];
    __shared__ __align__(16) unsigned short Pl[4][32 * 40];
    __shared__ float lsh[2][2][32];

    int pairi = blockIdx.x;
    int h = blockIdx.y;
    int kvh = h >> 2;
    int t = threadIdx.x;
    int w = t >> 6, lane = t & 63;
    int ln = lane & 15, q = lane >> 4;
    int qg = w >> 1, kg = w & 1;

    int nA = 64 - pairi;
    int bq = 63 - pairi;
    int wq0 = bq * 64;

    bf16x8 qf[2][4];
    {
        const unsigned short* qb0 = Qn + (size_t)(wq0 + qg * 32 + ln) * 2048 + h * 128;
        const unsigned short* qb1 = Qn + (size_t)(wq0 + qg * 32 + 16 + ln) * 2048 + h * 128;
#pragma unroll
        for (int kc = 0; kc < 4; ++kc) {
            qf[0][kc] = *(const bf16x8*)(qb0 + kc * 32 + q * 8);
            qf[1][kc] = *(const bf16x8*)(qb1 + kc * 32 + q * 8);
        }
    }

    f32x4 o[2][8] = {};
    f32x4 l_p[2] = {};

    const unsigned short* kbase[4];
    const unsigned short* vbase[4];
#pragma unroll
    for (int s = 0; s < 4; ++s) {
        int L = s * 256 + t;
        int key = L >> 4;
        int ck = (L & 15) ^ (key & 15);
        kbase[s] = Kn + (size_t)key * 512 + kvh * 128 + ck * 8;
        int hd = L >> 3;
        int cv = (L & 7) ^ (hd & 7);
        vbase[s] = Vt + (size_t)(kvh * 128 + hd) * 4096 + cv * 8;
    }

#pragma unroll
    for (int s = 0; s < 4; ++s) async_cp16(kbase[s], &Ks[0][s * 2048 + w * 512]);
#pragma unroll
    for (int s = 0; s < 4; ++s) async_cp16(vbase[s], &Vs[0][s * 2048 + w * 512]);

    for (int it = 0; it < 65; ++it) {
        __syncthreads();

        int nxt = it + 1;

        if (it == nA) {
            // ---- combine across kg pair + output; scratch = idle buffers [nxt&1] ----
            int fb = nxt & 1;
            float* osh = (qg == 0) ? (float*)&Ks[fb][0] : (float*)&Vs[fb][0];
            // write the half we do NOT own, with literal indices per branch
            if (kg == 0) {
#pragma unroll
                for (int qi = 0; qi < 2; ++qi)
#pragma unroll
                    for (int fi = 0; fi < 4; ++fi)
#pragma unroll
                        for (int r = 0; r < 4; ++r)
                            osh[((qi * 4 + fi) * 4 + r) * 64 + lane] = o[qi][fi + 4][r];
            } else {
#pragma unroll
                for (int qi = 0; qi < 2; ++qi)
#pragma unroll
                    for (int fi = 0; fi < 4; ++fi)
#pragma unroll
                        for (int r = 0; r < 4; ++r)
                            osh[2048 + ((qi * 4 + fi) * 4 + r) * 64 + lane] = o[qi][fi][r];
            }
            float l_red[2][4];
#pragma unroll
            for (int qi = 0; qi < 2; ++qi)
#pragma unroll
                for (int r = 0; r < 4; ++r) {
                    float s = l_p[qi][r];
                    s += __shfl_xor(s, 1); s += __shfl_xor(s, 2);
                    s += __shfl_xor(s, 4); s += __shfl_xor(s, 8);
                    l_red[qi][r] = s;
                    if (ln == 0) lsh[qg][kg][qi * 16 + q * 4 + r] = s;
                }
            __syncthreads();
            if (kg == 0) {
#pragma unroll
                for (int qi = 0; qi < 2; ++qi)
#pragma unroll
                    for (int r = 0; r < 4; ++r) {
                        float inv = 1.0f / (l_red[qi][r] + lsh[qg][1][qi * 16 + q * 4 + r]);
                        int row = wq0 + qg * 32 + qi * 16 + q * 4 + r;
                        unsigned short* ob = Ao + (size_t)row * 2048 + h * 128;
#pragma unroll
                        for (int fi = 0; fi < 4; ++fi) {
                            float v = o[qi][fi][r] + osh[2048 + ((qi * 4 + fi) * 4 + r) * 64 + lane];
                            ob[fi * 16 + ln] = f2bf(v * inv);
                        }
                    }
            } else {
#pragma unroll
                for (int qi = 0; qi < 2; ++qi)
#pragma unroll
                    for (int r = 0; r < 4; ++r) {
                        float inv = 1.0f / (l_red[qi][r] + lsh[qg][0][qi * 16 + q * 4 + r]);
                        int row = wq0 + qg * 32 + qi * 16 + q * 4 + r;
                        unsigned short* ob = Ao + (size_t)row * 2048 + h * 128;
#pragma unroll
                        for (int fi = 0; fi < 4; ++fi) {
                            float v = o[qi][fi + 4][r] + osh[((qi * 4 + fi) * 4 + r) * 64 + lane];
                            ob[(fi + 4) * 16 + ln] = f2bf(v * inv);
                        }
                    }
            }
            __syncthreads();
            // reset for second q-block
            bq = pairi; wq0 = bq * 64;
            const unsigned short* qb0 = Qn + (size_t)(wq0 + qg * 32 + ln) * 2048 + h * 128;
            const unsigned short* qb1 = Qn + (size_t)(wq0 + qg * 32 + 16 + ln) * 2048 + h * 128;
#pragma unroll
            for (int kc = 0; kc < 4; ++kc) {
                qf[0][kc] = *(const bf16x8*)(qb0 + kc * 32 + q * 8);
                qf[1][kc] = *(const bf16x8*)(qb1 + kc * 32 + q * 8);
            }
#pragma unroll
            for (int qi = 0; qi < 2; ++qi) {
#pragma unroll
                for (int f = 0; f < 8; ++f) o[qi][f] = (f32x4){0.f, 0.f, 0.f, 0.f};
                l_p[qi] = (f32x4){0.f, 0.f, 0.f, 0.f};
            }
        }

        if (nxt < 65) {
            int nkt = (nxt < nA) ? nxt * 64 : (nxt - nA) * 64;
            size_t koff = (size_t)nkt * 512;
            unsigned short* kd = Ks[nxt & 1];
            unsigned short* vd = Vs[nxt & 1];
#pragma unroll
            for (int s = 0; s < 4; ++s) async_cp16(kbase[s] + koff, kd + s * 2048 + w * 512);
#pragma unroll
            for (int s = 0; s < 4; ++s) async_cp16(vbase[s] + nkt, vd + s * 2048 + w * 512);
        }

        int kt0 = (it < nA) ? it * 64 : (it - nA) * 64;
        const unsigned short* kb = Ks[it & 1];
        const unsigned short* vb = Vs[it & 1];

        // QK^T: 2 q-tiles x 2 key-subtiles (this wave's 32-key half)
        f32x4 sA[2][2];
#pragma unroll
        for (int qi = 0; qi < 2; ++qi)
#pragma unroll
            for (int kj = 0; kj < 2; ++kj)
                sA[qi][kj] = (f32x4){-16.6f, -16.6f, -16.6f, -16.6f};

        __builtin_amdgcn_s_setprio(1);
#pragma unroll
        for (int kj = 0; kj < 2; ++kj) {
            int key = kg * 32 + kj * 16 + ln;
#pragma unroll
            for (int kc = 0; kc < 4; ++kc) {
                bf16x8 kf = *(const bf16x8*)(&kb[key * 128 + (((kc * 4 + q) ^ ln) * 8)]);
                sA[0][kj] = __builtin_amdgcn_mfma_f32_16x16x32_bf16(qf[0][kc], kf, sA[0][kj], 0, 0, 0);
                sA[1][kj] = __builtin_amdgcn_mfma_f32_16x16x32_bf16(qf[1][kc], kf, sA[1][kj], 0, 0, 0);
            }
        }
        __builtin_amdgcn_s_setprio(0);

        if (kt0 + kg * 32 + 31 > wq0 + qg * 32) {
#pragma unroll
            for (int qi = 0; qi < 2; ++qi)
#pragma unroll
                for (int kj = 0; kj < 2; ++kj)
#pragma unroll
                    for (int r = 0; r < 4; ++r) {
                        int key = kt0 + kg * 32 + kj * 16 + ln;
                        int row = wq0 + qg * 32 + qi * 16 + q * 4 + r;
                        if (key > row) sA[qi][kj][r] = -3e38f;
                    }
        }

#pragma unroll
        for (int qi = 0; qi < 2; ++qi)
#pragma unroll
            for (int r = 0; r < 4; ++r) {
                int prow = (qi * 16 + q * 4 + r) * 40;
#pragma unroll
                for (int kj = 0; kj < 2; ++kj) {
                    float p = __builtin_amdgcn_exp2f(sA[qi][kj][r]);
                    Pl[w][prow + kj * 16 + ln] = (unsigned short)(__float_as_uint(p) >> 16);
                    l_p[qi][r] += p;
                }
            }

        // PV: k-depth 32 (this wave's keys); each vf feeds both q-tiles
        bf16x8 pa0 = *(const bf16x8*)(&Pl[w][ln * 40 + q * 8]);
        bf16x8 pa1 = *(const bf16x8*)(&Pl[w][(16 + ln) * 40 + q * 8]);
        __builtin_amdgcn_s_setprio(1);
#pragma unroll
        for (int f = 0; f < 8; ++f) {
            bf16x8 vf = *(const bf16x8*)(&vb[(f * 16 + ln) * 64 + (((kg * 4 + q) ^ (ln & 7)) * 8)]);
            o[0][f] = __builtin_amdgcn_mfma_f32_16x16x32_bf16(pa0, vf, o[0][f], 0, 0, 0);
            o[1][f] = __builtin_amdgcn_mfma_f32_16x16x32_bf16(pa1, vf, o[1][f], 0, 0, 0);
        }
        __builtin_amdgcn_s_setprio(0);
    }

    // ---- final combine + output (scratch = buffers[1], both idle) ----
    {
        float* osh = (qg == 0) ? (float*)&Ks[1][0] : (float*)&Vs[1][0];
        if (kg == 0) {
#pragma unroll
            for (int qi = 0; qi < 2; ++qi)
#pragma unroll
                for (int fi = 0; fi < 4; ++fi)
#pragma unroll
                    for (int r = 0; r < 4; ++r)
                        osh[((qi * 4 + fi) * 4 + r) * 64 + lane] = o[qi][fi + 4][r];
        } else {
#pragma unroll
            for (int qi = 0; qi < 2; ++qi)
#pragma unroll
                for (int fi = 0; fi < 4; ++fi)
#pragma unroll
                    for (int r = 0; r < 4; ++r)
                        osh[2048 + ((qi * 4 + fi) * 4 + r) * 64 + lane] = o[qi][fi][r];
        }
        float l_red[2][4];
#pragma unroll
        for (int qi = 0; qi < 2; ++qi)
#pragma unroll
            for (int r = 0; r < 4; ++r) {
                float s = l_p[qi][r];
                s += __shfl_xor(s, 1); s += __shfl_xor(s, 2);
                s += __shfl_xor(s, 4); s += __shfl_xor(s, 8);
                l_red[qi][r] = s;
                if (ln == 0) lsh[qg][kg][qi * 16 + q * 4 + r] = s;
            }
        __syncthreads();
        if (kg == 0) {
#pragma unroll
            for (int qi = 0; qi < 2; ++qi)
#pragma unroll
                for (int r = 0; r < 4; ++r) {
                    float inv = 1.0f / (l_red[qi][r] + lsh[qg][1][qi * 16 + q * 4 + r]);
                    int row = wq0 + qg * 32 + qi * 16 + q * 4 + r;
                    unsigned short* ob = Ao + (size_t)row * 2048 + h * 128;
#pragma unroll
                    for (int fi = 0; fi < 4; ++fi) {
                        float v = o[qi][fi][r] + osh[2048 + ((qi * 4 + fi) * 4 + r) * 64 + lane];
                        ob[fi * 16 + ln] = f2bf(v * inv);
                    }
                }
        } else {
#pragma unroll
            for (int qi = 0; qi < 2; ++qi)
#pragma unroll
                for (int r = 0; r < 4; ++r) {
                    float inv = 1.0f / (l_red[qi][r] + lsh[qg][0][qi * 16 + q * 4 + r]);
                    int row = wq0 + qg * 32 + qi * 16 + q * 4 + r;
                    unsigned short* ob = Ao + (size_t)row * 2048 + h * 128;
#pragma unroll
                    for (int fi = 0; fi < 4; ++fi) {
                        float v = o[qi][fi + 4][r] + osh[((qi * 4 + fi) * 4 + r) * 64 + lane];
                        ob[(fi + 4) * 16 + ln] = f2bf(v * inv);
                    }
                }
        }
    }
}

extern "C" void kernel_launch(void* const* d_in, const int* in_sizes, int n_in,
                              void* d_out, int out_size, void* d_ws, size_t ws_size,
                              hipStream_t stream) {
    const float* x    = (const float*)d_in[0];
    const float* cosb = (const float*)d_in[1];
    const float* sinb = (const float*)d_in[2];
    const float* wq   = (const float*)d_in[3];
    const float* wk   = (const float*)d_in[4];
    const float* wv   = (const float*)d_in[5];
    const float* wo   = (const float*)d_in[6];
    float* out = (float*)d_out;

    char* ws = (char*)d_ws;
    unsigned short* xb    = (unsigned short*)ws;               // [4096][2048]
    unsigned short* wqkvT = xb    + (size_t)4096 * 2048;       // [3072][2048]
    unsigned short* woT   = wqkvT + (size_t)3072 * 2048;       // [2048][2048]
    unsigned short* Qn    = woT   + (size_t)2048 * 2048;       // [4096][2048]
    unsigned short* Kn    = Qn    + (size_t)4096 * 2048;       // [4096][512]
    unsigned short* Vt    = Kn    + (size_t)4096 * 512;        // [512][4096]
    unsigned short* Ao    = Vt    + (size_t)512 * 4096;        // [4096][2048]

    cvt_bf16<<<(4096 * 2048 / 4 + 255) / 256, 256, 0, stream>>>(x, xb, 4096 * 2048);
    transpose_all<<<dim3(64, 64, 4), dim3(32, 8), 0, stream>>>(wq, wk, wv, wo, wqkvT, woT);
    gemm_qkv<<<dim3(24, 32), 256, 0, stream>>>(xb, wqkvT, cosb, sinb, Qn, Kn, Vt);
    flash_attn<<<dim3(32, 16), 256, 0, stream>>>(Qn, Kn, Vt, Ao);
    gemm_bt_v12<<<dim3(16, 16), 512, 0, stream>>>(Ao, woT, out, 4096, 2048, 2048);
}

// Round 11
// 347.745 us; speedup vs baseline: 2.3426x; 1.0246x over previous
//
#include <hip/hip_runtime.h>

#define T_SEQ 4096
#define C_EMB 2048
#define NH 16
#define NKV 4
#define HD 128

typedef short bf16x8 __attribute__((ext_vector_type(8)));
typedef float f32x4 __attribute__((ext_vector_type(4)));
typedef unsigned short u16x4 __attribute__((ext_vector_type(4)));

__device__ inline unsigned short f2bf(float f) {
    unsigned int u = __float_as_uint(f);
    unsigned int r = (u + 0x7FFFu + ((u >> 16) & 1u)) >> 16;
    return (unsigned short)r;
}

// async global->LDS 16B per lane; lds base must be wave-uniform (lane*16 auto-added)
__device__ __forceinline__ void async_cp16(const unsigned short* g, unsigned short* l) {
    __builtin_amdgcn_global_load_lds((const __attribute__((address_space(1))) unsigned int*)g,
                                     (__attribute__((address_space(3))) unsigned int*)l,
                                     16, 0, 0);
}

// ---------------- merged prologue: fp32->bf16 cvt (z=4) + 4 weight transposes (z=0..3) ----------------
// One launch instead of two: removes a kernel boundary and lets cvt and transpose
// memory traffic overlap (both pure-bandwidth, independent outputs).
__global__ __launch_bounds__(256) void prologue(const float* __restrict__ x,
                                                const float* __restrict__ wq,
                                                const float* __restrict__ wk,
                                                const float* __restrict__ wv,
                                                const float* __restrict__ wo,
                                                unsigned short* __restrict__ xb,
                                                unsigned short* __restrict__ wqkvT,
                                                unsigned short* __restrict__ woT) {
    int z = blockIdx.z;
    if (z == 4) {
        // cvt slice: 4096 blocks x 256 threads x 8 floats = exactly 4096*2048
        int t = threadIdx.y * 32 + threadIdx.x;
        int b = blockIdx.y * 64 + blockIdx.x;
        size_t base = ((size_t)b * 256 + t) * 8;
        float4 f0 = *(const float4*)(&x[base]);
        float4 f1 = *(const float4*)(&x[base + 4]);
        u16x4 o0, o1;
        o0.x = f2bf(f0.x); o0.y = f2bf(f0.y); o0.z = f2bf(f0.z); o0.w = f2bf(f0.w);
        o1.x = f2bf(f1.x); o1.y = f2bf(f1.y); o1.z = f2bf(f1.z); o1.w = f2bf(f1.w);
        *(u16x4*)(&xb[base]) = o0;
        *(u16x4*)(&xb[base + 4]) = o1;
        return;
    }
    __shared__ float tile[32][33];
    const float* in;
    unsigned short* out;
    int ld_in;
    if (z == 0)      { in = wq; out = wqkvT;                         ld_in = 2048; }
    else if (z == 1) { in = wk; out = wqkvT + (size_t)2048 * 2048;   ld_in = 512;  }
    else if (z == 2) { in = wv; out = wqkvT + (size_t)2560 * 2048;   ld_in = 512;  }
    else             { in = wo; out = woT;                           ld_in = 2048; }
    if ((z == 1 || z == 2) && blockIdx.x >= 16) return;

    int x0 = blockIdx.x * 32 + threadIdx.x;
    for (int i = threadIdx.y; i < 32; i += 8) {
        int y = blockIdx.y * 32 + i;
        tile[i][threadIdx.x] = in[(size_t)y * ld_in + x0];
    }
    __syncthreads();
    int xo = blockIdx.y * 32 + threadIdx.x;
    for (int i = threadIdx.y; i < 32; i += 8) {
        int yo = blockIdx.x * 32 + i;
        out[(size_t)yo * 2048 + xo] = f2bf(tile[threadIdx.x][i]);
    }
}

// ==== Fused QKV projection + RoPE + RMSNorm + V-transpose (frozen from R5) ====
__global__ __launch_bounds__(256, 3) void gemm_qkv(const unsigned short* __restrict__ A,
                                                   const unsigned short* __restrict__ Bt,
                                                   const float* __restrict__ cosb,
                                                   const float* __restrict__ sinb,
                                                   unsigned short* __restrict__ Qn,
                                                   unsigned short* __restrict__ Kn,
                                                   unsigned short* __restrict__ Vt) {
    __shared__ __align__(16) unsigned short As[3][128 * 32];
    __shared__ __align__(16) unsigned short Bs[3][128 * 32];
    const int K = 2048;
    int t = threadIdx.x;
    int w = t >> 6, lane = t & 63;
    int ln = lane & 15, q = lane >> 4;
    int wm = w * 32;

    // XCD-rectangle swizzle: grid 24x32 = 768 = 8 XCDs x (12 cols x 8 rows)
    int d = blockIdx.y * 24 + blockIdx.x;
    int xcd = d & 7, l = d >> 3;
    int lx = l % 12, ly = l / 12;
    int bx = (xcd & 1) * 12 + lx;
    int by = (xcd >> 1) * 8 + ly;
    int m0 = by * 128, n0 = bx * 128;

    f32x4 acc[2][8] = {};

    int r0 = t >> 2, c0 = (t & 3) ^ ((t >> 4) & 3);
    int L1 = 256 + t;
    int r1 = L1 >> 2, c1 = (L1 & 3) ^ ((L1 >> 4) & 3);
    const unsigned short* a0 = &A[(size_t)(m0 + r0) * K + c0 * 8];
    const unsigned short* a1 = &A[(size_t)(m0 + r1) * K + c1 * 8];
    const unsigned short* b0 = &Bt[(size_t)(n0 + r0) * K + c0 * 8];
    const unsigned short* b1 = &Bt[(size_t)(n0 + r1) * K + c1 * 8];

    auto stage = [&](int b, int k0) {
        async_cp16(a0 + k0, &As[b][w * 512]);
        async_cp16(a1 + k0, &As[b][2048 + w * 512]);
        async_cp16(b0 + k0, &Bs[b][w * 512]);
        async_cp16(b1 + k0, &Bs[b][2048 + w * 512]);
    };

    stage(0, 0);
    stage(1, 32);

    int bc = 0;
    for (int it = 0; it < 64; ++it) {
        if (it < 63) asm volatile("s_waitcnt vmcnt(4)" ::: "memory");
        else         asm volatile("s_waitcnt vmcnt(0)" ::: "memory");
        __builtin_amdgcn_s_barrier();
        __builtin_amdgcn_sched_barrier(0);
        if (it < 62) {
            int bn = bc + 2; if (bn >= 3) bn -= 3;
            stage(bn, (it + 2) * 32);
        }
        int cs = (q ^ ((ln >> 2) & 3)) * 8;
        bf16x8 af[2], bfr[8];
#pragma unroll
        for (int i = 0; i < 2; ++i) af[i] = *(const bf16x8*)(&As[bc][(wm + i * 16 + ln) * 32 + cs]);
#pragma unroll
        for (int j = 0; j < 8; ++j) bfr[j] = *(const bf16x8*)(&Bs[bc][(j * 16 + ln) * 32 + cs]);
#pragma unroll
        for (int i = 0; i < 2; ++i)
#pragma unroll
            for (int j = 0; j < 8; ++j)
                acc[i][j] = __builtin_amdgcn_mfma_f32_16x16x32_bf16(af[i], bfr[j], acc[i][j], 0, 0, 0);
        bc = (bc == 2) ? 0 : bc + 1;
    }

    // ---- fused epilogue ----
    if (n0 < 2560) {
        bool isQ = (n0 < 2048);
        int h = isQ ? (n0 >> 7) : ((n0 - 2048) >> 7);
#pragma unroll
        for (int i = 0; i < 2; ++i)
#pragma unroll
            for (int r = 0; r < 4; ++r) {
                int row = m0 + wm + i * 16 + q * 4 + r;
                float y1[4], y2[4];
                float ss = 0.0f;
#pragma unroll
                for (int j = 0; j < 4; ++j) {
                    float a = acc[i][j][r];
                    float b = acc[i][j + 4][r];
                    float cc = cosb[row * 64 + j * 16 + ln];
                    float sv = sinb[row * 64 + j * 16 + ln];
                    y1[j] = a * cc + b * sv;
                    y2[j] = b * cc - a * sv;
                    ss += y1[j] * y1[j] + y2[j] * y2[j];
                }
                ss += __shfl_xor(ss, 1);
                ss += __shfl_xor(ss, 2);
                ss += __shfl_xor(ss, 4);
                ss += __shfl_xor(ss, 8);
                float rv = rsqrtf(ss * (1.0f / 128.0f) + 1e-6f);
                if (isQ) {
                    float s = rv * (0.08838834764831845f * 1.4426950408889634f);
                    unsigned short* ob = Qn + (size_t)row * 2048 + h * 128;
#pragma unroll
                    for (int j = 0; j < 4; ++j) {
                        ob[j * 16 + ln] = f2bf(y1[j] * s);
                        ob[64 + j * 16 + ln] = f2bf(y2[j] * s);
                    }
                } else {
                    unsigned short* ob = Kn + (size_t)row * 512 + h * 128;
#pragma unroll
                    for (int j = 0; j < 4; ++j) {
                        ob[j * 16 + ln] = f2bf(y1[j] * rv);
                        ob[64 + j * 16 + ln] = f2bf(y2[j] * rv);
                    }
                }
            }
    } else {
        int v0 = n0 - 2560;
        unsigned short* sm = &As[0][0];
#pragma unroll
        for (int half = 0; half < 2; ++half) {
            __syncthreads();
#pragma unroll
            for (int i = 0; i < 2; ++i)
#pragma unroll
                for (int jj = 0; jj < 4; ++jj) {
                    int j = half * 4 + jj;
                    int cc = jj * 16 + ln;
                    int rr = wm + i * 16 + q * 4;
                    u16x4 pk;
                    pk.x = f2bf(acc[i][j][0]); pk.y = f2bf(acc[i][j][1]);
                    pk.z = f2bf(acc[i][j][2]); pk.w = f2bf(acc[i][j][3]);
                    *(u16x4*)(&sm[cc * 136 + rr]) = pk;
                }
            __syncthreads();
            int vtr = t >> 2, mseg = (t & 3) * 32;
            unsigned short* dst = Vt + (size_t)(v0 + half * 64 + vtr) * 4096 + m0 + mseg;
            const unsigned short* src = &sm[vtr * 136 + mseg];
            *(int4*)(dst)      = *(const int4*)(src);
            *(int4*)(dst + 8)  = *(const int4*)(src + 8);
            *(int4*)(dst + 16) = *(const int4*)(src + 16);
            *(int4*)(dst + 24) = *(const int4*)(src + 24);
        }
    }
}

// ---------------- bf16 GEMM (out-proj) v12 (frozen from R8) ----------------
__global__ __launch_bounds__(512, 2) void gemm_bt_v12(const unsigned short* __restrict__ A,
                                                      const unsigned short* __restrict__ Bt,
                                                      float* __restrict__ C, int M, int N, int K) {
    __shared__ __align__(16) unsigned short As[2][256 * 64];
    __shared__ __align__(16) unsigned short Bs[2][128 * 64];
    int t = threadIdx.x;
    int w = t >> 6, lane = t & 63;
    int ln = lane & 15, q = lane >> 4;
    int wr = w >> 1, wc = w & 1;
    int m0 = blockIdx.y * 256, n0 = blockIdx.x * 128;

    f32x4 acc[4][4] = {};

    const unsigned short* ab[4];
    const unsigned short* bb[2];
#pragma unroll
    for (int s = 0; s < 4; ++s) {
        int L = s * 512 + t;
        int r = L >> 3;
        int c = (L & 7) ^ (r & 7);
        ab[s] = &A[(size_t)(m0 + r) * K + c * 8];
    }
#pragma unroll
    for (int s = 0; s < 2; ++s) {
        int L = s * 512 + t;
        int r = L >> 3;
        int c = (L & 7) ^ (r & 7);
        bb[s] = &Bt[(size_t)(n0 + r) * K + c * 8];
    }

    auto stage = [&](int b, int k0) {
#pragma unroll
        for (int s = 0; s < 4; ++s) async_cp16(ab[s] + k0, &As[b][s * 4096 + w * 512]);
#pragma unroll
        for (int s = 0; s < 2; ++s) async_cp16(bb[s] + k0, &Bs[b][s * 4096 + w * 512]);
    };

    stage(0, 0);
    asm volatile("s_waitcnt vmcnt(0)" ::: "memory");
    __builtin_amdgcn_s_barrier();

    int buf = 0;
    for (int it = 0; it < 32; ++it) {
        if (it < 31) stage(buf ^ 1, (it + 1) * 64);
#pragma unroll
        for (int kk = 0; kk < 2; ++kk) {
            bf16x8 bfr[4];
#pragma unroll
            for (int j = 0; j < 4; ++j) {
                int row = wc * 64 + j * 16 + ln;
                bfr[j] = *(const bf16x8*)(&Bs[buf][row * 64 + (((kk * 4 + q) ^ (row & 7)) * 8)]);
            }
#pragma unroll
            for (int i = 0; i < 4; ++i) {
                int row = wr * 64 + i * 16 + ln;
                bf16x8 a = *(const bf16x8*)(&As[buf][row * 64 + (((kk * 4 + q) ^ (row & 7)) * 8)]);
#pragma unroll
                for (int j = 0; j < 4; ++j)
                    acc[i][j] = __builtin_amdgcn_mfma_f32_16x16x32_bf16(a, bfr[j], acc[i][j], 0, 0, 0);
            }
        }
        asm volatile("s_waitcnt vmcnt(0)" ::: "memory");
        __builtin_amdgcn_s_barrier();
        buf ^= 1;
    }

#pragma unroll
    for (int i = 0; i < 4; ++i)
#pragma unroll
        for (int j = 0; j < 4; ++j)
#pragma unroll
            for (int r = 0; r < 4; ++r) {
                int row = m0 + wr * 64 + i * 16 + q * 4 + r;
                int col = n0 + wc * 64 + j * 16 + ln;
                C[(size_t)row * N + col] = acc[i][j][r];
            }
}

// ---------------- Flash attention v4.1 (reverted: best measured 120.5 us) ----------------
__global__ __launch_bounds__(256) void flash_attn(const unsigned short* __restrict__ Qn,
                                                  const unsigned short* __restrict__ Kn,
                                                  const unsigned short* __restrict__ Vt,
                                                  unsigned short* __restrict__ Ao) {
    __shared__ __align__(16) unsigned short Ks[2][64 * 128];
    __shared__ __align__(16) unsigned short Vs[2][128 * 64];
    __shared__ __align__(16) unsigned short Pl[4][16 * 72];

    int pairi = blockIdx.x;
    int h = blockIdx.y;
    int kvh = h >> 2;
    int t = threadIdx.x;
    int w = t >> 6, lane = t & 63;
    int ln = lane & 15, q = lane >> 4;

    int nA = 64 - pairi;
    int bq = 63 - pairi;
    int wq0 = bq * 64 + w * 16;

    bf16x8 qf[4];
    {
        const unsigned short* qb = Qn + (size_t)(wq0 + ln) * 2048 + h * 128;
#pragma unroll
        for (int kc = 0; kc < 4; ++kc) qf[kc] = *(const bf16x8*)(qb + kc * 32 + q * 8);
    }

    f32x4 o[8] = {};
    f32x4 l_p = {0.f, 0.f, 0.f, 0.f};

    const unsigned short* kbase[4];
    const unsigned short* vbase[4];
#pragma unroll
    for (int s = 0; s < 4; ++s) {
        int L = s * 256 + t;
        int key = L >> 4;
        int ck = (L & 15) ^ (key & 15);
        kbase[s] = Kn + (size_t)key * 512 + kvh * 128 + ck * 8;
        int hd = L >> 3;
        int cv = (L & 7) ^ (hd & 7);
        vbase[s] = Vt + (size_t)(kvh * 128 + hd) * 4096 + cv * 8;
    }

#pragma unroll
    for (int s = 0; s < 4; ++s) async_cp16(kbase[s], &Ks[0][s * 2048 + w * 512]);
#pragma unroll
    for (int s = 0; s < 4; ++s) async_cp16(vbase[s], &Vs[0][s * 2048 + w * 512]);

    for (int it = 0; it < 65; ++it) {
        __syncthreads();

        int nxt = it + 1;
        if (nxt < 65) {
            int nkt = (nxt < nA) ? nxt * 64 : (nxt - nA) * 64;
            size_t koff = (size_t)nkt * 512;
            unsigned short* kd = Ks[nxt & 1];
            unsigned short* vd = Vs[nxt & 1];
#pragma unroll
            for (int s = 0; s < 4; ++s) async_cp16(kbase[s] + koff, kd + s * 2048 + w * 512);
#pragma unroll
            for (int s = 0; s < 4; ++s) async_cp16(vbase[s] + nkt, vd + s * 2048 + w * 512);
        }

        if (it == nA) {
#pragma unroll
            for (int r = 0; r < 4; ++r) {
                float lsum = l_p[r];
                lsum += __shfl_xor(lsum, 1);
                lsum += __shfl_xor(lsum, 2);
                lsum += __shfl_xor(lsum, 4);
                lsum += __shfl_xor(lsum, 8);
                float inv = 1.0f / lsum;
                int row = wq0 + q * 4 + r;
                unsigned short* ob = Ao + (size_t)row * 2048 + h * 128;
#pragma unroll
                for (int f = 0; f < 8; ++f) ob[f * 16 + ln] = f2bf(o[f][r] * inv);
            }
            bq = pairi;
            wq0 = bq * 64 + w * 16;
            const unsigned short* qb = Qn + (size_t)(wq0 + ln) * 2048 + h * 128;
#pragma unroll
            for (int kc = 0; kc < 4; ++kc) qf[kc] = *(const bf16x8*)(qb + kc * 32 + q * 8);
#pragma unroll
            for (int f = 0; f < 8; ++f) o[f] = (f32x4){0.f, 0.f, 0.f, 0.f};
            l_p = (f32x4){0.f, 0.f, 0.f, 0.f};
        }

        int kt0 = (it < nA) ? it * 64 : (it - nA) * 64;
        const unsigned short* kb = Ks[it & 1];
        const unsigned short* vb = Vs[it & 1];

        f32x4 sA[4] = {{-16.6f, -16.6f, -16.6f, -16.6f}, {-16.6f, -16.6f, -16.6f, -16.6f},
                       {-16.6f, -16.6f, -16.6f, -16.6f}, {-16.6f, -16.6f, -16.6f, -16.6f}};
        __builtin_amdgcn_s_setprio(1);
#pragma unroll
        for (int jt = 0; jt < 4; ++jt) {
            int key = jt * 16 + ln;
#pragma unroll
            for (int kc = 0; kc < 4; ++kc) {
                int cs = ((kc * 4 + q) ^ ln) * 8;
                bf16x8 kf = *(const bf16x8*)(&kb[key * 128 + cs]);
                sA[jt] = __builtin_amdgcn_mfma_f32_16x16x32_bf16(qf[kc], kf, sA[jt], 0, 0, 0);
            }
        }
        __builtin_amdgcn_s_setprio(0);
        if (kt0 + 63 > wq0) {
#pragma unroll
            for (int jt = 0; jt < 4; ++jt)
#pragma unroll
                for (int r = 0; r < 4; ++r) {
                    int key = kt0 + jt * 16 + ln;
                    int row = wq0 + q * 4 + r;
                    if (key > row) sA[jt][r] = -3e38f;
                }
        }
#pragma unroll
        for (int r = 0; r < 4; ++r) {
            int prow = (q * 4 + r) * 72;
#pragma unroll
            for (int jt = 0; jt < 4; ++jt) {
                float p = __builtin_amdgcn_exp2f(sA[jt][r]);
                Pl[w][prow + jt * 16 + ln] = (unsigned short)(__float_as_uint(p) >> 16);
                l_p[r] += p;
            }
        }

        __builtin_amdgcn_s_setprio(1);
#pragma unroll
        for (int ks = 0; ks < 2; ++ks) {
            bf16x8 pa = *(const bf16x8*)(&Pl[w][ln * 72 + ks * 32 + q * 8]);
            int cs = ((ks * 4 + q) ^ (ln & 7)) * 8;
#pragma unroll
            for (int f = 0; f < 8; ++f) {
                bf16x8 vf = *(const bf16x8*)(&vb[(f * 16 + ln) * 64 + cs]);
                o[f] = __builtin_amdgcn_mfma_f32_16x16x32_bf16(pa, vf, o[f], 0, 0, 0);
            }
        }
        __builtin_amdgcn_s_setprio(0);
    }
#pragma unroll
    for (int r = 0; r < 4; ++r) {
        float lsum = l_p[r];
        lsum += __shfl_xor(lsum, 1);
        lsum += __shfl_xor(lsum, 2);
        lsum += __shfl_xor(lsum, 4);
        lsum += __shfl_xor(lsum, 8);
        float inv = 1.0f / lsum;
        int row = wq0 + q * 4 + r;
        unsigned short* ob = Ao + (size_t)row * 2048 + h * 128;
#pragma unroll
        for (int f = 0; f < 8; ++f) ob[f * 16 + ln] = f2bf(o[f][r] * inv);
    }
}

extern "C" void kernel_launch(void* const* d_in, const int* in_sizes, int n_in,
                              void* d_out, int out_size, void* d_ws, size_t ws_size,
                              hipStream_t stream) {
    const float* x    = (const float*)d_in[0];
    const float* cosb = (const float*)d_in[1];
    const float* sinb = (const float*)d_in[2];
    const float* wq   = (const float*)d_in[3];
    const float* wk   = (const float*)d_in[4];
    const float* wv   = (const float*)d_in[5];
    const float* wo   = (const float*)d_in[6];
    float* out = (float*)d_out;

    char* ws = (char*)d_ws;
    unsigned short* xb    = (unsigned short*)ws;               // [4096][2048]
    unsigned short* wqkvT = xb    + (size_t)4096 * 2048;       // [3072][2048]
    unsigned short* woT   = wqkvT + (size_t)3072 * 2048;       // [2048][2048]
    unsigned short* Qn    = woT   + (size_t)2048 * 2048;       // [4096][2048]
    unsigned short* Kn    = Qn    + (size_t)4096 * 2048;       // [4096][512]
    unsigned short* Vt    = Kn    + (size_t)4096 * 512;        // [512][4096]
    unsigned short* Ao    = Vt    + (size_t)512 * 4096;        // [4096][2048]

    prologue<<<dim3(64, 64, 5), dim3(32, 8), 0, stream>>>(x, wq, wk, wv, wo, xb, wqkvT, woT);
    gemm_qkv<<<dim3(24, 32), 256, 0, stream>>>(xb, wqkvT, cosb, sinb, Qn, Kn, Vt);
    flash_attn<<<dim3(32, 16), 256, 0, stream>>>(Qn, Kn, Vt, Ao);
    gemm_bt_v12<<<dim3(16, 16), 512, 0, stream>>>(Ao, woT, out, 4096, 2048, 2048);
}